// Round 1
// baseline (1471.686 us; speedup 1.0000x reference)
//
#include <hip/hip_runtime.h>
#include <hip/hip_bf16.h>

// RGCN classifier, MI355X. Round 1: bf16 MFMA GEMMs + atomic scatter baseline.
// ws layout (bytes):
//   XW   @ 0          : 65536*1152*2 = 150,994,944  (bf16, 8 rel cols + self col)
//   agg  @ 150994944  : 65536*128*4  =  33,554,432  (fp32 atomic target)
//   hb   @ 184549376  : 65536*128*2  =  16,777,216  (h bf16; reused as h2 bf16)
//   h1b  @ 201326592  : 65536*128*2  =  16,777,216
//   Wt1  @ 218103808  : 9*16384*2    =     294,912  (transposed bf16 weights)
//   Wt2  @ 218398720  : 9*16384*2    =     294,912
// total ~218.7 MB

#define N_NODES 65536
#define N_EDGES 786432
#define DIM 128
#define NT 9
#define XW_LD (NT * DIM) /* 1152 */
#define N_GRAPHS 64

typedef unsigned int uint;
typedef unsigned short ushort;
typedef __attribute__((ext_vector_type(8))) short short8;
typedef __attribute__((ext_vector_type(4))) float f32x4;

__device__ inline ushort f2b(float f) {
  uint u = __float_as_uint(f);
  u += 0x7fff + ((u >> 16) & 1);   // RNE
  return (ushort)(u >> 16);
}
__device__ inline float b2f(ushort h) { return __uint_as_float(((uint)h) << 16); }

__device__ inline void gl_lds16(const void* g, void* l) {
  __builtin_amdgcn_global_load_lds(
      (const __attribute__((address_space(1))) unsigned int*)g,
      (__attribute__((address_space(3))) unsigned int*)l, 16, 0, 0);
}

// ---------------- conversions ----------------
__global__ __launch_bounds__(256) void f32_to_bf16_vec(const float* __restrict__ x,
                                                       ushort* __restrict__ y, int n4) {
  int i = blockIdx.x * 256 + threadIdx.x;
  if (i >= n4) return;
  float4 v = ((const float4*)x)[i];
  ushort4 o;
  o.x = f2b(v.x); o.y = f2b(v.y); o.z = f2b(v.z); o.w = f2b(v.w);
  ((ushort4*)y)[i] = o;
}

// Wt[tile][n][k] = W[tile][k][n], bf16
__global__ __launch_bounds__(256) void wconv_t(const float* __restrict__ W,
                                               ushort* __restrict__ Wt) {
  int tile = blockIdx.x;
  const float* S = W + (size_t)tile * 16384;
  ushort* D = Wt + (size_t)tile * 16384;
  for (int i = threadIdx.x; i < 16384; i += 256) {
    int n = i >> 7, k = i & 127;
    D[i] = f2b(S[k * 128 + n]);
  }
}

__global__ __launch_bounds__(256) void zero_f32(float* __restrict__ p, int n4) {
  int i = blockIdx.x * 256 + threadIdx.x;
  if (i < n4) ((float4*)p)[i] = (float4){0.f, 0.f, 0.f, 0.f};
}

// ---------------- GEMM: C[M,NT*128] = A[M,128] @ Wt^T, bf16 MFMA ----------------
// 128x128 tile, whole K=128 staged once. LDS: A 32KB + B 32KB, XOR-swizzled via
// pre-swizzled global source (linear global_load_lds dest) + swizzled ds_read.
__global__ __launch_bounds__(256) void gemm128(const ushort* __restrict__ A,
                                               const ushort* __restrict__ Bt,
                                               ushort* __restrict__ C, int ldc) {
  __shared__ char lds[65536];
  const int bm = blockIdx.x, bn = blockIdx.y;
  const char* Ag = (const char*)(A + (size_t)bm * 128 * 128);
  const char* Bg = (const char*)(Bt + (size_t)bn * 128 * 128);
  const int tid = threadIdx.x;
  const int wv = tid >> 6, ln = tid & 63;

#pragma unroll
  for (int it = 0; it < 8; ++it) {
    int chunk = it * 4096 + wv * 1024;          // wave-uniform LDS base
    int p = chunk + ln * 16;                    // linear lds byte pos of this lane
    int ps = p ^ (((p >> 8) & 7) << 4);         // inverse-swizzled global source
    gl_lds16(Ag + ps, lds + chunk);
    gl_lds16(Bg + ps, lds + 32768 + chunk);
  }
  asm volatile("s_waitcnt vmcnt(0)" ::: "memory");
  __syncthreads();

  const int wm = wv >> 1, wn = wv & 1;          // 2x2 waves, 64x64 each
  const int lr = ln & 15, kq = ln >> 4;
  f32x4 acc[4][4];
#pragma unroll
  for (int m = 0; m < 4; ++m)
#pragma unroll
    for (int n = 0; n < 4; ++n) acc[m][n] = (f32x4){0.f, 0.f, 0.f, 0.f};

#pragma unroll
  for (int kk = 0; kk < 4; ++kk) {
    const int kb = kk * 64 + kq * 16;           // byte offset within 256B row
    short8 a[4], b[4];
#pragma unroll
    for (int m = 0; m < 4; ++m) {
      int row = wm * 64 + m * 16 + lr;
      int off = row * 256 + kb;
      a[m] = *(const short8*)(lds + (off ^ ((row & 7) << 4)));
    }
#pragma unroll
    for (int n = 0; n < 4; ++n) {
      int col = wn * 64 + n * 16 + lr;
      int off = col * 256 + kb;
      b[n] = *(const short8*)(lds + 32768 + (off ^ ((col & 7) << 4)));
    }
#pragma unroll
    for (int m = 0; m < 4; ++m)
#pragma unroll
      for (int n = 0; n < 4; ++n)
        acc[m][n] = __builtin_amdgcn_mfma_f32_16x16x32_bf16(a[m], b[n], acc[m][n], 0, 0, 0);
  }

#pragma unroll
  for (int m = 0; m < 4; ++m) {
    int row0 = bm * 128 + wm * 64 + m * 16 + kq * 4;
#pragma unroll
    for (int n = 0; n < 4; ++n) {
      int col = bn * 128 + wn * 64 + n * 16 + lr;
#pragma unroll
      for (int e = 0; e < 4; ++e)
        C[(size_t)(row0 + e) * ldc + col] = f2b(acc[m][n][e]);
    }
  }
}

// ---------------- edge scatter: agg[dst] += XW[src, etype] ----------------
__global__ __launch_bounds__(256) void scatter_edges(const ushort* __restrict__ XW,
                                                     const int* __restrict__ src,
                                                     const int* __restrict__ dst,
                                                     const int* __restrict__ et,
                                                     float* __restrict__ agg) {
  int t = blockIdx.x * 256 + threadIdx.x;
  int e = t >> 6, l = t & 63;
  if (e >= N_EDGES) return;
  int s = src[e], d = dst[e], r = et[e];
  uint v = *(const uint*)(XW + (size_t)s * XW_LD + r * DIM + l * 2);
  float* ap = agg + (size_t)d * DIM + l * 2;
  atomicAdd(ap, b2f((ushort)(v & 0xffff)));
  atomicAdd(ap + 1, b2f((ushort)(v >> 16)));
}

// ---------------- epilogue: h_out = relu(agg + self + b) -> bf16 ----------------
__global__ __launch_bounds__(256) void epilogue(const float* __restrict__ agg,
                                                const ushort* __restrict__ XW,
                                                const float* __restrict__ bias,
                                                ushort* __restrict__ hout) {
  int i = blockIdx.x * 256 + threadIdx.x;  // handles elems 2i, 2i+1
  int base = i << 1;
  int n = base >> 7, d = base & 127;
  float2 a = *(const float2*)(agg + base);
  uint sv = *(const uint*)(XW + (size_t)n * XW_LD + 1024 + d);
  float x0 = fmaxf(a.x + b2f((ushort)(sv & 0xffffu)) + bias[d], 0.f);
  float x1 = fmaxf(a.y + b2f((ushort)(sv >> 16)) + bias[d + 1], 0.f);
  uint o = (uint)f2b(x0) | ((uint)f2b(x1) << 16);
  *(uint*)(hout + base) = o;
}

// ---------------- per-graph max pool + classifier ----------------
__global__ __launch_bounds__(256) void pool_classify(const ushort* __restrict__ h2,
                                                     const float* __restrict__ Wc,
                                                     const float* __restrict__ bc,
                                                     float* __restrict__ out) {
  __shared__ float red[16][128];
  __shared__ float pooled[128];
  int g = blockIdx.x;
  int tid = threadIdx.x;
  int c = tid & 15, r = tid >> 4;
  float mx[8];
#pragma unroll
  for (int j = 0; j < 8; ++j) mx[j] = 0.f;  // post-ReLU values are >= 0
  const ushort* base = h2 + ((size_t)g << 10) * DIM;
  for (int node = r; node < 1024; node += 16) {
    short8 v = *(const short8*)(base + node * DIM + c * 8);
#pragma unroll
    for (int j = 0; j < 8; ++j) mx[j] = fmaxf(mx[j], b2f((ushort)v[j]));
  }
#pragma unroll
  for (int j = 0; j < 8; ++j) red[r][c * 8 + j] = mx[j];
  __syncthreads();
  if (tid < 128) {
    float m = 0.f;
#pragma unroll
    for (int rr = 0; rr < 16; ++rr) m = fmaxf(m, red[rr][tid]);
    pooled[tid] = m;
  }
  __syncthreads();
  if (tid < 10) {
    float s = bc[tid];
    for (int d2 = 0; d2 < DIM; ++d2) s += pooled[d2] * Wc[d2 * 10 + tid];
    out[g * 10 + tid] = s;
  }
}

extern "C" void kernel_launch(void* const* d_in, const int* in_sizes, int n_in,
                              void* d_out, int out_size, void* d_ws, size_t ws_size,
                              hipStream_t stream) {
  const float* h       = (const float*)d_in[0];
  const float* W1      = (const float*)d_in[1];
  const float* W1_self = (const float*)d_in[2];
  const float* b1      = (const float*)d_in[3];
  const float* W2      = (const float*)d_in[4];
  const float* W2_self = (const float*)d_in[5];
  const float* b2      = (const float*)d_in[6];
  const float* Wc      = (const float*)d_in[7];
  const float* bc      = (const float*)d_in[8];
  const int* src   = (const int*)d_in[9];
  const int* dst   = (const int*)d_in[10];
  const int* etype = (const int*)d_in[11];
  float* out = (float*)d_out;

  char* ws = (char*)d_ws;
  ushort* XW  = (ushort*)(ws);
  float*  agg = (float*)(ws + 150994944);
  ushort* hb  = (ushort*)(ws + 184549376);   // h bf16, later reused for h2
  ushort* h1b = (ushort*)(ws + 201326592);
  ushort* Wt1 = (ushort*)(ws + 218103808);
  ushort* Wt2 = (ushort*)(ws + 218398720);

  const int n4_h   = N_NODES * DIM / 4;      // 2,097,152
  const int g_h    = n4_h / 256;             // 8192
  const int g_sc   = N_EDGES * 64 / 256;     // 196,608
  const int g_epi  = N_NODES * DIM / 2 / 256; // 16,384
  dim3 gemm_grid(N_NODES / 128, NT);

  // --- prep: bf16 conversions + weight transposes ---
  f32_to_bf16_vec<<<g_h, 256, 0, stream>>>(h, hb, n4_h);
  wconv_t<<<8, 256, 0, stream>>>(W1, Wt1);
  wconv_t<<<1, 256, 0, stream>>>(W1_self, Wt1 + 8 * 16384);
  wconv_t<<<8, 256, 0, stream>>>(W2, Wt2);
  wconv_t<<<1, 256, 0, stream>>>(W2_self, Wt2 + 8 * 16384);

  // --- layer 1 ---
  gemm128<<<gemm_grid, 256, 0, stream>>>(hb, Wt1, XW, XW_LD);
  zero_f32<<<g_h, 256, 0, stream>>>(agg, n4_h);
  scatter_edges<<<g_sc, 256, 0, stream>>>(XW, src, dst, etype, agg);
  epilogue<<<g_epi, 256, 0, stream>>>(agg, XW, b1, h1b);

  // --- layer 2 (h2 overwrites hb) ---
  gemm128<<<gemm_grid, 256, 0, stream>>>(h1b, Wt2, XW, XW_LD);
  zero_f32<<<g_h, 256, 0, stream>>>(agg, n4_h);
  scatter_edges<<<g_sc, 256, 0, stream>>>(XW, src, dst, etype, agg);
  epilogue<<<g_epi, 256, 0, stream>>>(agg, XW, b2, hb);

  // --- pool + classify ---
  pool_classify<<<N_GRAPHS, 256, 0, stream>>>(hb, Wc, bc, out);

  (void)in_sizes; (void)n_in; (void)out_size; (void)ws_size;
}

// Round 2
// 359.631 us; speedup vs baseline: 4.0922x; 4.0922x over previous
//
#include <hip/hip_runtime.h>
#include <hip/hip_bf16.h>

// RGCN classifier, MI355X. Round 2: gather-first restructure, no atomics on features.
// out[v] = relu( Wcat^T @ [ sum_r-aggregated h | self h ] + b ), Wcat = [W_r...; W_self]
// ws layout (bytes):
//   aggB  @ 0          : 65536*1152*2 = 150,994,944  (bf16: 8 rel-sums + self)
//   hb    @ 150994944  : 16,777,216   (h bf16)
//   h1b   @ 167772160  : 16,777,216
//   hb2   @ 184549376  : 16,777,216
//   Wt1c  @ 201326592  : 294,912      (bf16 [n=128][k=1152])
//   Wt2c  @ 201621504  : 294,912
//   deg   @ 201916416  : 262,144
//   offs  @ 202178560  : 262,144
//   cursor@ 202440704  : 262,144
//   bsum  @ 202702848  : 1,024
//   meta  @ 202703872  : 3,145,728    (packed src<<3|etype, CSR by dst)
// total ~205.8 MB

#define N_NODES 65536
#define N_EDGES 786432
#define DIM 128
#define NT 9
#define XW_LD (NT * DIM) /* 1152 */
#define N_GRAPHS 64

typedef unsigned int uint;
typedef unsigned short ushort;
typedef __attribute__((ext_vector_type(8))) short short8;
typedef __attribute__((ext_vector_type(4))) float f32x4;

__device__ inline ushort f2b(float f) {
  uint u = __float_as_uint(f);
  u += 0x7fff + ((u >> 16) & 1);   // RNE
  return (ushort)(u >> 16);
}
__device__ inline float b2f(ushort h) { return __uint_as_float(((uint)h) << 16); }

__device__ inline void gl_lds16(const void* g, void* l) {
  __builtin_amdgcn_global_load_lds(
      (const __attribute__((address_space(1))) unsigned int*)g,
      (__attribute__((address_space(3))) unsigned int*)l, 16, 0, 0);
}

// ---------------- conversions ----------------
__global__ __launch_bounds__(256) void f32_to_bf16_vec(const float* __restrict__ x,
                                                       ushort* __restrict__ y, int n4) {
  int i = blockIdx.x * 256 + threadIdx.x;
  if (i >= n4) return;
  float4 v = ((const float4*)x)[i];
  ushort4 o;
  o.x = f2b(v.x); o.y = f2b(v.y); o.z = f2b(v.z); o.w = f2b(v.w);
  ((ushort4*)y)[i] = o;
}

// Wt[n][tile*128+k] = W[tile][k][n], bf16, concatenated K layout
__global__ __launch_bounds__(256) void wconv_cat(const float* __restrict__ W,
                                                 ushort* __restrict__ Wt, int tile0) {
  int tile = tile0 + blockIdx.x;
  const float* S = W + (size_t)blockIdx.x * 16384;
  for (int i = threadIdx.x; i < 16384; i += 256) {
    int n = i >> 7, k = i & 127;
    Wt[(size_t)n * XW_LD + tile * 128 + k] = f2b(S[k * 128 + n]);
  }
}

// ---------------- CSR build ----------------
__global__ __launch_bounds__(256) void zero_i32(int* __restrict__ p, int n) {
  int i = blockIdx.x * 256 + threadIdx.x;
  if (i < n) p[i] = 0;
}
__global__ __launch_bounds__(256) void hist_dst(const int* __restrict__ dst,
                                                int* __restrict__ deg) {
  int e = blockIdx.x * 256 + threadIdx.x;
  if (e < N_EDGES) atomicAdd(&deg[dst[e]], 1);
}
__global__ __launch_bounds__(256) void scan_block(const int* __restrict__ deg,
                                                  int* __restrict__ offs,
                                                  int* __restrict__ bsum) {
  __shared__ int s[256];
  int t = threadIdx.x, i = blockIdx.x * 256 + t;
  int v = deg[i];
  s[t] = v; __syncthreads();
  for (int d = 1; d < 256; d <<= 1) {
    int x = (t >= d) ? s[t - d] : 0; __syncthreads();
    s[t] += x; __syncthreads();
  }
  offs[i] = s[t] - v;            // exclusive within block
  if (t == 255) bsum[blockIdx.x] = s[t];
}
__global__ __launch_bounds__(256) void scan_bsum(int* __restrict__ bsum) {
  __shared__ int s[256];
  int t = threadIdx.x;
  int v = bsum[t];
  s[t] = v; __syncthreads();
  for (int d = 1; d < 256; d <<= 1) {
    int x = (t >= d) ? s[t - d] : 0; __syncthreads();
    s[t] += x; __syncthreads();
  }
  bsum[t] = s[t] - v;            // exclusive
}
__global__ __launch_bounds__(256) void add_offs(int* __restrict__ offs,
                                                const int* __restrict__ bsum,
                                                int* __restrict__ cursor) {
  int i = blockIdx.x * 256 + threadIdx.x;
  int o = offs[i] + bsum[blockIdx.x];
  offs[i] = o; cursor[i] = o;
}
__global__ __launch_bounds__(256) void fill_meta(const int* __restrict__ src,
                                                 const int* __restrict__ dst,
                                                 const int* __restrict__ et,
                                                 int* __restrict__ cursor,
                                                 uint* __restrict__ meta) {
  int e = blockIdx.x * 256 + threadIdx.x;
  if (e >= N_EDGES) return;
  int p = atomicAdd(&cursor[dst[e]], 1);
  meta[p] = ((uint)src[e] << 3) | (uint)et[e];
}

// ---------------- gather: aggB[v] = [ sum_{e in r} h[src] for r=0..7 | h[v] ] ----------------
__global__ __launch_bounds__(256) void gather_agg(const ushort* __restrict__ hb,
                                                  const uint* __restrict__ meta,
                                                  const int* __restrict__ offs,
                                                  const int* __restrict__ deg,
                                                  ushort* __restrict__ aggB) {
  int node = (blockIdx.x * 256 + threadIdx.x) >> 6;
  int ln = threadIdx.x & 63;
  int start = __builtin_amdgcn_readfirstlane(offs[node]);
  int ne = __builtin_amdgcn_readfirstlane(deg[node]);
  float a0[8] = {0.f,0.f,0.f,0.f,0.f,0.f,0.f,0.f};
  float a1[8] = {0.f,0.f,0.f,0.f,0.f,0.f,0.f,0.f};
  for (int i = 0; i < ne; ++i) {
    uint m = (uint)__builtin_amdgcn_readfirstlane((int)meta[start + i]);
    uint s = m >> 3;
    int r = (int)(m & 7u);
    uint hv = *(const uint*)(hb + (size_t)s * DIM + ln * 2);
    float x0 = b2f((ushort)(hv & 0xffffu));
    float x1 = b2f((ushort)(hv >> 16));
    switch (r) {   // wave-uniform branch; static reg indexing (no scratch)
      case 0: a0[0]+=x0; a1[0]+=x1; break;
      case 1: a0[1]+=x0; a1[1]+=x1; break;
      case 2: a0[2]+=x0; a1[2]+=x1; break;
      case 3: a0[3]+=x0; a1[3]+=x1; break;
      case 4: a0[4]+=x0; a1[4]+=x1; break;
      case 5: a0[5]+=x0; a1[5]+=x1; break;
      case 6: a0[6]+=x0; a1[6]+=x1; break;
      case 7: a0[7]+=x0; a1[7]+=x1; break;
    }
  }
  ushort* out = aggB + (size_t)node * XW_LD + ln * 2;
#pragma unroll
  for (int r = 0; r < 8; ++r) {
    uint o = (uint)f2b(a0[r]) | ((uint)f2b(a1[r]) << 16);
    *(uint*)(out + r * DIM) = o;
  }
  *(uint*)(out + 8 * DIM) = *(const uint*)(hb + (size_t)node * DIM + ln * 2);
}

// ---------------- GEMM: C[65536,128] = relu(aggB[65536,1152] @ Wt^T + bias) -> bf16 ----
// 128x128 tile (one N-tile), K-loop of 18 x BK=64. LDS 32KB, XOR-swizzled staging.
__global__ __launch_bounds__(256) void gemm_agg(const ushort* __restrict__ A,
                                                const ushort* __restrict__ Bt,
                                                const float* __restrict__ bias,
                                                ushort* __restrict__ C) {
  __shared__ char lds[32768];   // A tile [128][128B] @0, B tile [128][128B] @16384
  const int bm = blockIdx.x;
  const char* Ag = (const char*)(A + (size_t)bm * 128 * XW_LD);
  const char* Bg = (const char*)Bt;
  const int tid = threadIdx.x, wv = tid >> 6, ln = tid & 63;
  const int wm = wv >> 1, wn = wv & 1, lr = ln & 15, kq = ln >> 4;
  f32x4 acc[4][4];
#pragma unroll
  for (int m = 0; m < 4; ++m)
#pragma unroll
    for (int n = 0; n < 4; ++n) acc[m][n] = (f32x4){0.f, 0.f, 0.f, 0.f};

  for (int kt = 0; kt < 18; ++kt) {
    __syncthreads();                       // prior-iter reads done before overwrite
#pragma unroll
    for (int it = 0; it < 4; ++it) {
      int chunk = (wv * 4 + it) * 1024;    // wave-uniform LDS base
      int p = chunk + ln * 16;
      int row = p >> 7, inb = p & 127;
      int swz = inb ^ ((row & 7) << 4);    // pre-swizzled global source
      size_t gb = (size_t)row * 2304 + (size_t)kt * 128 + swz;
      gl_lds16(Ag + gb, lds + chunk);
      gl_lds16(Bg + gb, lds + 16384 + chunk);
    }
    asm volatile("s_waitcnt vmcnt(0)" ::: "memory");
    __syncthreads();
#pragma unroll
    for (int k2 = 0; k2 < 2; ++k2) {
      const int kb = k2 * 64 + kq * 16;
      short8 a[4], b[4];
#pragma unroll
      for (int m = 0; m < 4; ++m) {
        int row = wm * 64 + m * 16 + lr;
        a[m] = *(const short8*)(lds + ((row * 128 + kb) ^ ((row & 7) << 4)));
      }
#pragma unroll
      for (int n = 0; n < 4; ++n) {
        int col = wn * 64 + n * 16 + lr;
        b[n] = *(const short8*)(lds + 16384 + ((col * 128 + kb) ^ ((col & 7) << 4)));
      }
#pragma unroll
      for (int m = 0; m < 4; ++m)
#pragma unroll
        for (int n = 0; n < 4; ++n)
          acc[m][n] = __builtin_amdgcn_mfma_f32_16x16x32_bf16(a[m], b[n], acc[m][n], 0, 0, 0);
    }
  }

#pragma unroll
  for (int m = 0; m < 4; ++m) {
    int row0 = bm * 128 + wm * 64 + m * 16 + kq * 4;
#pragma unroll
    for (int n = 0; n < 4; ++n) {
      int col = wn * 64 + n * 16 + lr;
      float bv = bias[col];
#pragma unroll
      for (int e = 0; e < 4; ++e)
        C[(size_t)(row0 + e) * 128 + col] = f2b(fmaxf(acc[m][n][e] + bv, 0.f));
    }
  }
}

// ---------------- per-graph max pool + classifier ----------------
__global__ __launch_bounds__(256) void pool_classify(const ushort* __restrict__ h2,
                                                     const float* __restrict__ Wc,
                                                     const float* __restrict__ bc,
                                                     float* __restrict__ out) {
  __shared__ float red[16][128];
  __shared__ float pooled[128];
  int g = blockIdx.x;
  int tid = threadIdx.x;
  int c = tid & 15, r = tid >> 4;
  float mx[8];
#pragma unroll
  for (int j = 0; j < 8; ++j) mx[j] = 0.f;  // post-ReLU values >= 0
  const ushort* base = h2 + ((size_t)g << 10) * DIM;
  for (int node = r; node < 1024; node += 16) {
    short8 v = *(const short8*)(base + node * DIM + c * 8);
#pragma unroll
    for (int j = 0; j < 8; ++j) mx[j] = fmaxf(mx[j], b2f((ushort)v[j]));
  }
#pragma unroll
  for (int j = 0; j < 8; ++j) red[r][c * 8 + j] = mx[j];
  __syncthreads();
  if (tid < 128) {
    float m = 0.f;
#pragma unroll
    for (int rr = 0; rr < 16; ++rr) m = fmaxf(m, red[rr][tid]);
    pooled[tid] = m;
  }
  __syncthreads();
  if (tid < 10) {
    float s = bc[tid];
    for (int d2 = 0; d2 < DIM; ++d2) s += pooled[d2] * Wc[d2 * 10 + tid];
    out[g * 10 + tid] = s;
  }
}

extern "C" void kernel_launch(void* const* d_in, const int* in_sizes, int n_in,
                              void* d_out, int out_size, void* d_ws, size_t ws_size,
                              hipStream_t stream) {
  const float* h       = (const float*)d_in[0];
  const float* W1      = (const float*)d_in[1];
  const float* W1_self = (const float*)d_in[2];
  const float* b1      = (const float*)d_in[3];
  const float* W2      = (const float*)d_in[4];
  const float* W2_self = (const float*)d_in[5];
  const float* b2      = (const float*)d_in[6];
  const float* Wc      = (const float*)d_in[7];
  const float* bc      = (const float*)d_in[8];
  const int* src   = (const int*)d_in[9];
  const int* dst   = (const int*)d_in[10];
  const int* etype = (const int*)d_in[11];
  float* out = (float*)d_out;

  char* ws = (char*)d_ws;
  ushort* aggB  = (ushort*)(ws);
  ushort* hb    = (ushort*)(ws + 150994944);
  ushort* h1b   = (ushort*)(ws + 167772160);
  ushort* hb2   = (ushort*)(ws + 184549376);
  ushort* Wt1c  = (ushort*)(ws + 201326592);
  ushort* Wt2c  = (ushort*)(ws + 201621504);
  int*    deg   = (int*)(ws + 201916416);
  int*    offs  = (int*)(ws + 202178560);
  int*    cursor= (int*)(ws + 202440704);
  int*    bsum  = (int*)(ws + 202702848);
  uint*   meta  = (uint*)(ws + 202703872);

  const int n4_h = N_NODES * DIM / 4;            // 2,097,152
  const int g_h = n4_h / 256;                    // 8192
  const int g_edge = (N_EDGES + 255) / 256;      // 3072
  const int g_gather = N_NODES / 4;              // 16384 (4 waves/block)

  // --- prep: conversions + weights ---
  f32_to_bf16_vec<<<g_h, 256, 0, stream>>>(h, hb, n4_h);
  wconv_cat<<<8, 256, 0, stream>>>(W1, Wt1c, 0);
  wconv_cat<<<1, 256, 0, stream>>>(W1_self, Wt1c, 8);
  wconv_cat<<<8, 256, 0, stream>>>(W2, Wt2c, 0);
  wconv_cat<<<1, 256, 0, stream>>>(W2_self, Wt2c, 8);

  // --- CSR by dst (shared by both layers) ---
  zero_i32<<<256, 256, 0, stream>>>(deg, N_NODES);
  hist_dst<<<g_edge, 256, 0, stream>>>(dst, deg);
  scan_block<<<256, 256, 0, stream>>>(deg, offs, bsum);
  scan_bsum<<<1, 256, 0, stream>>>(bsum);
  add_offs<<<256, 256, 0, stream>>>(offs, bsum, cursor);
  fill_meta<<<g_edge, 256, 0, stream>>>(src, dst, etype, cursor, meta);

  // --- layer 1 ---
  gather_agg<<<g_gather, 256, 0, stream>>>(hb, meta, offs, deg, aggB);
  gemm_agg<<<N_NODES / 128, 256, 0, stream>>>(aggB, Wt1c, b1, h1b);

  // --- layer 2 ---
  gather_agg<<<g_gather, 256, 0, stream>>>(h1b, meta, offs, deg, aggB);
  gemm_agg<<<N_NODES / 128, 256, 0, stream>>>(aggB, Wt2c, b2, hb2);

  // --- pool + classify ---
  pool_classify<<<N_GRAPHS, 256, 0, stream>>>(hb2, Wc, bc, out);

  (void)in_sizes; (void)n_in; (void)out_size; (void)ws_size;
}

// Round 3
// 305.078 us; speedup vs baseline: 4.8240x; 1.1788x over previous
//
#include <hip/hip_runtime.h>
#include <hip/hip_bf16.h>

// RGCN classifier, MI355X. Round 3: latency-optimized gather (meta preload +
// readlane + 4-deep load pipelining), double-buffered GEMM, pool split.
// ws layout (bytes):
//   aggB  @ 0          : 65536*1152*2 = 150,994,944  (bf16: 8 rel-sums + self)
//   hb    @ 150994944  : 16,777,216   (h bf16)
//   h1b   @ 167772160  : 16,777,216
//   hb2   @ 184549376  : 16,777,216
//   Wt1c  @ 201326592  : 294,912      (bf16 [n=128][k=1152])
//   Wt2c  @ 201621504  : 294,912
//   deg   @ 201916416  : 262,144
//   offs  @ 202178560  : 262,144
//   cursor@ 202440704  : 262,144
//   bsum  @ 202702848  : 1,024
//   meta  @ 202703872  : 3,145,728    (packed src<<3|etype, CSR by dst)
//   partial@205849600  : 262,144      (pool partials f32[512][128])
// total ~206.1 MB

#define N_NODES 65536
#define N_EDGES 786432
#define DIM 128
#define NT 9
#define XW_LD (NT * DIM) /* 1152 */
#define N_GRAPHS 64

typedef unsigned int uint;
typedef unsigned short ushort;
typedef __attribute__((ext_vector_type(8))) short short8;
typedef __attribute__((ext_vector_type(4))) float f32x4;

__device__ inline ushort f2b(float f) {
  uint u = __float_as_uint(f);
  u += 0x7fff + ((u >> 16) & 1);   // RNE
  return (ushort)(u >> 16);
}
__device__ inline float b2f(ushort h) { return __uint_as_float(((uint)h) << 16); }

__device__ inline void gl_lds16(const void* g, void* l) {
  __builtin_amdgcn_global_load_lds(
      (const __attribute__((address_space(1))) unsigned int*)g,
      (__attribute__((address_space(3))) unsigned int*)l, 16, 0, 0);
}

// ---------------- conversions ----------------
__global__ __launch_bounds__(256) void f32_to_bf16_vec(const float* __restrict__ x,
                                                       ushort* __restrict__ y, int n4) {
  int i = blockIdx.x * 256 + threadIdx.x;
  if (i >= n4) return;
  float4 v = ((const float4*)x)[i];
  ushort4 o;
  o.x = f2b(v.x); o.y = f2b(v.y); o.z = f2b(v.z); o.w = f2b(v.w);
  ((ushort4*)y)[i] = o;
}

// All weight tiles -> concatenated-K bf16 layout in one launch (18 blocks)
__global__ __launch_bounds__(256) void wconv_all(const float* __restrict__ W1,
                                                 const float* __restrict__ W1s,
                                                 const float* __restrict__ W2,
                                                 const float* __restrict__ W2s,
                                                 ushort* __restrict__ Wt1,
                                                 ushort* __restrict__ Wt2) {
  int b = blockIdx.x;  // 0..17
  const float* S;
  ushort* D;
  int tile;
  if (b < 9) { D = Wt1; tile = b; S = (b < 8) ? (W1 + (size_t)b * 16384) : W1s; }
  else       { D = Wt2; tile = b - 9; S = (tile < 8) ? (W2 + (size_t)tile * 16384) : W2s; }
  for (int i = threadIdx.x; i < 16384; i += 256) {
    int n = i >> 7, k = i & 127;
    D[(size_t)n * XW_LD + tile * 128 + k] = f2b(S[k * 128 + n]);
  }
}

// ---------------- CSR build ----------------
__global__ __launch_bounds__(256) void hist_dst(const int* __restrict__ dst,
                                                int* __restrict__ deg) {
  int e = blockIdx.x * 256 + threadIdx.x;
  if (e < N_EDGES) atomicAdd(&deg[dst[e]], 1);
}
__global__ __launch_bounds__(256) void scan_block(const int* __restrict__ deg,
                                                  int* __restrict__ offs,
                                                  int* __restrict__ bsum) {
  __shared__ int s[256];
  int t = threadIdx.x, i = blockIdx.x * 256 + t;
  int v = deg[i];
  s[t] = v; __syncthreads();
  for (int d = 1; d < 256; d <<= 1) {
    int x = (t >= d) ? s[t - d] : 0; __syncthreads();
    s[t] += x; __syncthreads();
  }
  offs[i] = s[t] - v;
  if (t == 255) bsum[blockIdx.x] = s[t];
}
__global__ __launch_bounds__(256) void scan_bsum(int* __restrict__ bsum) {
  __shared__ int s[256];
  int t = threadIdx.x;
  int v = bsum[t];
  s[t] = v; __syncthreads();
  for (int d = 1; d < 256; d <<= 1) {
    int x = (t >= d) ? s[t - d] : 0; __syncthreads();
    s[t] += x; __syncthreads();
  }
  bsum[t] = s[t] - v;
}
__global__ __launch_bounds__(256) void add_offs(int* __restrict__ offs,
                                                const int* __restrict__ bsum,
                                                int* __restrict__ cursor) {
  int i = blockIdx.x * 256 + threadIdx.x;
  int o = offs[i] + bsum[blockIdx.x];
  offs[i] = o; cursor[i] = o;
}
__global__ __launch_bounds__(256) void fill_meta(const int* __restrict__ src,
                                                 const int* __restrict__ dst,
                                                 const int* __restrict__ et,
                                                 int* __restrict__ cursor,
                                                 uint* __restrict__ meta) {
  int e = blockIdx.x * 256 + threadIdx.x;
  if (e >= N_EDGES) return;
  int p = atomicAdd(&cursor[dst[e]], 1);
  meta[p] = ((uint)src[e] << 3) | (uint)et[e];
}

// ---------------- gather: aggB[v] = [ sum_{e in r} h[src] for r=0..7 | h[v] ] --------
// Wave per node. Cooperative meta preload (1 vector load per 64 edges), readlane
// broadcast, 4-deep independent h-loads. No atomics.
#define ACC(r, v)                                                             \
  do {                                                                        \
    float x0 = b2f((ushort)((v) & 0xffffu));                                  \
    float x1 = b2f((ushort)((v) >> 16));                                      \
    switch (r) {                                                              \
      case 0: a0[0] += x0; a1[0] += x1; break;                                \
      case 1: a0[1] += x0; a1[1] += x1; break;                                \
      case 2: a0[2] += x0; a1[2] += x1; break;                                \
      case 3: a0[3] += x0; a1[3] += x1; break;                                \
      case 4: a0[4] += x0; a1[4] += x1; break;                                \
      case 5: a0[5] += x0; a1[5] += x1; break;                                \
      case 6: a0[6] += x0; a1[6] += x1; break;                                \
      case 7: a0[7] += x0; a1[7] += x1; break;                                \
    }                                                                         \
  } while (0)

__global__ __launch_bounds__(256) void gather_agg(const ushort* __restrict__ hb,
                                                  const uint* __restrict__ meta,
                                                  const int* __restrict__ offs,
                                                  const int* __restrict__ deg,
                                                  ushort* __restrict__ aggB) {
  int node = (blockIdx.x * 256 + threadIdx.x) >> 6;
  int ln = threadIdx.x & 63;
  int start = __builtin_amdgcn_readfirstlane(offs[node]);
  int ne = __builtin_amdgcn_readfirstlane(deg[node]);
  const uint* hw = (const uint*)hb;  // node row = 64 uints (2 bf16 each)
  float a0[8] = {0.f, 0.f, 0.f, 0.f, 0.f, 0.f, 0.f, 0.f};
  float a1[8] = {0.f, 0.f, 0.f, 0.f, 0.f, 0.f, 0.f, 0.f};

  for (int c = 0; c < ne; c += 64) {
    int nc = ne - c;
    if (nc > 64) nc = 64;
    uint mv = meta[start + c + (ln < nc ? ln : nc - 1)];  // wave preload
    int i = 0;
    for (; i + 4 <= nc; i += 4) {
      uint m0 = (uint)__builtin_amdgcn_readlane((int)mv, i + 0);
      uint m1 = (uint)__builtin_amdgcn_readlane((int)mv, i + 1);
      uint m2 = (uint)__builtin_amdgcn_readlane((int)mv, i + 2);
      uint m3 = (uint)__builtin_amdgcn_readlane((int)mv, i + 3);
      uint v0 = hw[(size_t)(m0 >> 3) * 64 + ln];
      uint v1 = hw[(size_t)(m1 >> 3) * 64 + ln];
      uint v2 = hw[(size_t)(m2 >> 3) * 64 + ln];
      uint v3 = hw[(size_t)(m3 >> 3) * 64 + ln];
      ACC((int)(m0 & 7u), v0);
      ACC((int)(m1 & 7u), v1);
      ACC((int)(m2 & 7u), v2);
      ACC((int)(m3 & 7u), v3);
    }
    for (; i < nc; ++i) {
      uint m = (uint)__builtin_amdgcn_readlane((int)mv, i);
      uint v = hw[(size_t)(m >> 3) * 64 + ln];
      ACC((int)(m & 7u), v);
    }
  }

  ushort* out = aggB + (size_t)node * XW_LD + ln * 2;
#pragma unroll
  for (int r = 0; r < 8; ++r) {
    uint o = (uint)f2b(a0[r]) | ((uint)f2b(a1[r]) << 16);
    *(uint*)(out + r * DIM) = o;
  }
  *(uint*)(out + 8 * DIM) = hw[(size_t)node * 64 + ln];
}

// ---------------- GEMM: C[65536,128] = relu(aggB[65536,1152] @ Wt^T + bias) -> bf16 --
// 128x128 tile, K-loop 18 x BK=64, double-buffered LDS (2x32KB), swizzled staging.
__global__ __launch_bounds__(256) void gemm_agg(const ushort* __restrict__ A,
                                                const ushort* __restrict__ Bt,
                                                const float* __restrict__ bias,
                                                ushort* __restrict__ C) {
  __shared__ char lds[65536];  // buf0: A@0 B@16384 ; buf1: A@32768 B@49152
  const int bm = blockIdx.x;
  const char* Ag = (const char*)(A + (size_t)bm * 128 * XW_LD);
  const char* Bg = (const char*)Bt;
  const int tid = threadIdx.x, wv = tid >> 6, ln = tid & 63;
  const int wm = wv >> 1, wn = wv & 1, lr = ln & 15, kq = ln >> 4;

  f32x4 acc[4][4];
#pragma unroll
  for (int m = 0; m < 4; ++m)
#pragma unroll
    for (int n = 0; n < 4; ++n) acc[m][n] = (f32x4){0.f, 0.f, 0.f, 0.f};

#define STAGE(kt, buf)                                                        \
  do {                                                                        \
    _Pragma("unroll")                                                         \
    for (int it = 0; it < 4; ++it) {                                          \
      int chunk = (wv * 4 + it) * 1024;                                       \
      int p = chunk + ln * 16;                                                \
      int row = p >> 7, inb = p & 127;                                        \
      int swz = inb ^ ((row & 7) << 4);                                       \
      size_t gb = (size_t)row * 2304 + (size_t)(kt) * 128 + swz;              \
      gl_lds16(Ag + gb, lds + (buf) * 32768 + chunk);                         \
      gl_lds16(Bg + gb, lds + (buf) * 32768 + 16384 + chunk);                 \
    }                                                                         \
  } while (0)

  STAGE(0, 0);
  asm volatile("s_waitcnt vmcnt(0)" ::: "memory");
  __syncthreads();

  for (int kt = 0; kt < 18; ++kt) {
    int buf = kt & 1;
    if (kt + 1 < 18) STAGE(kt + 1, buf ^ 1);  // prefetch next tile
    const char* la = lds + buf * 32768;
    const char* lb = la + 16384;
#pragma unroll
    for (int k2 = 0; k2 < 2; ++k2) {
      const int kb = k2 * 64 + kq * 16;
      short8 a[4], b[4];
#pragma unroll
      for (int m = 0; m < 4; ++m) {
        int row = wm * 64 + m * 16 + lr;
        a[m] = *(const short8*)(la + ((row * 128 + kb) ^ ((row & 7) << 4)));
      }
#pragma unroll
      for (int n = 0; n < 4; ++n) {
        int col = wn * 64 + n * 16 + lr;
        b[n] = *(const short8*)(lb + ((col * 128 + kb) ^ ((col & 7) << 4)));
      }
#pragma unroll
      for (int m = 0; m < 4; ++m)
#pragma unroll
        for (int n = 0; n < 4; ++n)
          acc[m][n] = __builtin_amdgcn_mfma_f32_16x16x32_bf16(a[m], b[n], acc[m][n], 0, 0, 0);
    }
    asm volatile("s_waitcnt vmcnt(0)" ::: "memory");
    __syncthreads();
  }

#pragma unroll
  for (int m = 0; m < 4; ++m) {
    int row0 = bm * 128 + wm * 64 + m * 16 + kq * 4;
#pragma unroll
    for (int n = 0; n < 4; ++n) {
      int col = wn * 64 + n * 16 + lr;
      float bv = bias[col];
#pragma unroll
      for (int e = 0; e < 4; ++e)
        C[(size_t)(row0 + e) * 128 + col] = f2b(fmaxf(acc[m][n][e] + bv, 0.f));
    }
  }
}

// ---------------- pool (2-stage) + classifier ----------------
// stage 1: 512 blocks, each max-reduces 128 nodes -> partial[block][128] f32
__global__ __launch_bounds__(256) void pool_partial(const ushort* __restrict__ h2,
                                                    float* __restrict__ partial) {
  __shared__ float red[8][128];
  int blk = blockIdx.x, tid = threadIdx.x;
  int c = tid & 31, r = tid >> 5;  // c: dim-quad, r: row-group of 8
  float mx[4] = {0.f, 0.f, 0.f, 0.f};  // post-ReLU >= 0
  const ushort* base = h2 + (size_t)blk * 128 * DIM;
  for (int node = r; node < 128; node += 8) {
    ushort4 v = *(const ushort4*)(base + node * DIM + c * 4);
    mx[0] = fmaxf(mx[0], b2f(v.x));
    mx[1] = fmaxf(mx[1], b2f(v.y));
    mx[2] = fmaxf(mx[2], b2f(v.z));
    mx[3] = fmaxf(mx[3], b2f(v.w));
  }
#pragma unroll
  for (int j = 0; j < 4; ++j) red[r][c * 4 + j] = mx[j];
  __syncthreads();
  if (tid < 128) {
    float m = 0.f;
#pragma unroll
    for (int rr = 0; rr < 8; ++rr) m = fmaxf(m, red[rr][tid]);
    partial[(size_t)blk * 128 + tid] = m;
  }
}
// stage 2: 64 blocks x 128 threads: max over 8 partials, then dot with Wc
__global__ __launch_bounds__(128) void classify(const float* __restrict__ partial,
                                                const float* __restrict__ Wc,
                                                const float* __restrict__ bc,
                                                float* __restrict__ out) {
  __shared__ float pooled[128];
  int g = blockIdx.x, tid = threadIdx.x;
  const float* p = partial + (size_t)g * 8 * 128;
  float m = 0.f;
#pragma unroll
  for (int b = 0; b < 8; ++b) m = fmaxf(m, p[b * 128 + tid]);
  pooled[tid] = m;
  __syncthreads();
  if (tid < 10) {
    float s = bc[tid];
    for (int d = 0; d < DIM; ++d) s += pooled[d] * Wc[d * 10 + tid];
    out[g * 10 + tid] = s;
  }
}

extern "C" void kernel_launch(void* const* d_in, const int* in_sizes, int n_in,
                              void* d_out, int out_size, void* d_ws, size_t ws_size,
                              hipStream_t stream) {
  const float* h       = (const float*)d_in[0];
  const float* W1      = (const float*)d_in[1];
  const float* W1_self = (const float*)d_in[2];
  const float* b1      = (const float*)d_in[3];
  const float* W2      = (const float*)d_in[4];
  const float* W2_self = (const float*)d_in[5];
  const float* b2      = (const float*)d_in[6];
  const float* Wc      = (const float*)d_in[7];
  const float* bc      = (const float*)d_in[8];
  const int* src   = (const int*)d_in[9];
  const int* dst   = (const int*)d_in[10];
  const int* etype = (const int*)d_in[11];
  float* out = (float*)d_out;

  char* ws = (char*)d_ws;
  ushort* aggB   = (ushort*)(ws);
  ushort* hb     = (ushort*)(ws + 150994944);
  ushort* h1b    = (ushort*)(ws + 167772160);
  ushort* hb2    = (ushort*)(ws + 184549376);
  ushort* Wt1c   = (ushort*)(ws + 201326592);
  ushort* Wt2c   = (ushort*)(ws + 201621504);
  int*    deg    = (int*)(ws + 201916416);
  int*    offs   = (int*)(ws + 202178560);
  int*    cursor = (int*)(ws + 202440704);
  int*    bsum   = (int*)(ws + 202702848);
  uint*   meta   = (uint*)(ws + 202703872);
  float*  partial= (float*)(ws + 205849600);

  const int n4_h = N_NODES * DIM / 4;        // 2,097,152
  const int g_h = n4_h / 256;                // 8192
  const int g_edge = (N_EDGES + 255) / 256;  // 3072
  const int g_gather = N_NODES / 4;          // 16384 (4 waves/block)

  // --- prep ---
  f32_to_bf16_vec<<<g_h, 256, 0, stream>>>(h, hb, n4_h);
  wconv_all<<<18, 256, 0, stream>>>(W1, W1_self, W2, W2_self, Wt1c, Wt2c);

  // --- CSR by dst (shared by both layers) ---
  hipMemsetAsync(deg, 0, N_NODES * sizeof(int), stream);
  hist_dst<<<g_edge, 256, 0, stream>>>(dst, deg);
  scan_block<<<256, 256, 0, stream>>>(deg, offs, bsum);
  scan_bsum<<<1, 256, 0, stream>>>(bsum);
  add_offs<<<256, 256, 0, stream>>>(offs, bsum, cursor);
  fill_meta<<<g_edge, 256, 0, stream>>>(src, dst, etype, cursor, meta);

  // --- layer 1 ---
  gather_agg<<<g_gather, 256, 0, stream>>>(hb, meta, offs, deg, aggB);
  gemm_agg<<<N_NODES / 128, 256, 0, stream>>>(aggB, Wt1c, b1, h1b);

  // --- layer 2 ---
  gather_agg<<<g_gather, 256, 0, stream>>>(h1b, meta, offs, deg, aggB);
  gemm_agg<<<N_NODES / 128, 256, 0, stream>>>(aggB, Wt2c, b2, hb2);

  // --- pool + classify ---
  pool_partial<<<512, 256, 0, stream>>>(hb2, partial);
  classify<<<N_GRAPHS, 128, 0, stream>>>(partial, Wc, bc, out);

  (void)in_sizes; (void)n_in; (void)out_size; (void)ws_size;
}

// Round 4
// 282.661 us; speedup vs baseline: 5.2065x; 1.0793x over previous
//
#include <hip/hip_runtime.h>
#include <hip/hip_bf16.h>

// RGCN classifier, MI355X. Round 4: transform-first (XW = h @ Wcat via MFMA GEMM),
// then CSR gather of 256B XW rows straight into the 128-dim output (2 fp32
// accumulators/lane, no relation switch, no atomics), fused self+bias+relu.
// ws layout (bytes):
//   XW    @ 0          : 65536*1152*2 = 150,994,944  (bf16 [node][1152])
//   hb    @ 150994944  : 16,777,216   (h bf16)
//   h1b   @ 167772160  : 16,777,216
//   hb2   @ 184549376  : 16,777,216
//   Wt1c  @ 201326592  : 294,912      (bf16 [1152][128]: [tile*128+n][k])
//   Wt2c  @ 201621504  : 294,912
//   deg   @ 201916416  : 262,144
//   offs  @ 202178560  : 262,144
//   cursor@ 202440704  : 262,144
//   bsum  @ 202702848  : 1,024
//   meta  @ 202703872  : 3,145,728    (uint offset src*576 + et*64 into XW-as-u32)
//   partial@205849600  : 262,144
// total ~206.1 MB

#define N_NODES 65536
#define N_EDGES 786432
#define DIM 128
#define NT 9
#define XW_LD (NT * DIM) /* 1152 */
#define N_GRAPHS 64

typedef unsigned int uint;
typedef unsigned short ushort;
typedef __attribute__((ext_vector_type(8))) short short8;
typedef __attribute__((ext_vector_type(4))) float f32x4;

__device__ inline ushort f2b(float f) {
  uint u = __float_as_uint(f);
  u += 0x7fff + ((u >> 16) & 1);   // RNE
  return (ushort)(u >> 16);
}
__device__ inline float b2f(ushort h) { return __uint_as_float(((uint)h) << 16); }
__device__ inline float blo(uint v) { return __uint_as_float(v << 16); }
__device__ inline float bhi(uint v) { return __uint_as_float(v & 0xffff0000u); }

__device__ inline void gl_lds16(const void* g, void* l) {
  __builtin_amdgcn_global_load_lds(
      (const __attribute__((address_space(1))) unsigned int*)g,
      (__attribute__((address_space(3))) unsigned int*)l, 16, 0, 0);
}

// ---------------- conversions ----------------
__global__ __launch_bounds__(256) void f32_to_bf16_vec(const float* __restrict__ x,
                                                       ushort* __restrict__ y, int n4) {
  int i = blockIdx.x * 256 + threadIdx.x;
  if (i >= n4) return;
  float4 v = ((const float4*)x)[i];
  ushort4 o;
  o.x = f2b(v.x); o.y = f2b(v.y); o.z = f2b(v.z); o.w = f2b(v.w);
  ((ushort4*)y)[i] = o;
}

// Weights -> bf16 [tile*128+n][k] (B^T tiles, contiguous per output-col tile)
__global__ __launch_bounds__(256) void wconv_all(const float* __restrict__ W1,
                                                 const float* __restrict__ W1s,
                                                 const float* __restrict__ W2,
                                                 const float* __restrict__ W2s,
                                                 ushort* __restrict__ Wt1,
                                                 ushort* __restrict__ Wt2) {
  int b = blockIdx.x;  // 0..17
  const float* S;
  ushort* D;
  int tile;
  if (b < 9) { D = Wt1; tile = b; S = (b < 8) ? (W1 + (size_t)b * 16384) : W1s; }
  else       { D = Wt2; tile = b - 9; S = (tile < 8) ? (W2 + (size_t)tile * 16384) : W2s; }
  for (int i = threadIdx.x; i < 16384; i += 256) {
    int n = i >> 7, k = i & 127;
    D[((size_t)tile * 128 + n) * 128 + k] = f2b(S[k * 128 + n]);
  }
}

// ---------------- CSR build ----------------
__global__ __launch_bounds__(256) void hist_dst(const int* __restrict__ dst,
                                                int* __restrict__ deg) {
  int e = blockIdx.x * 256 + threadIdx.x;
  if (e < N_EDGES) atomicAdd(&deg[dst[e]], 1);
}
__global__ __launch_bounds__(256) void scan_block(const int* __restrict__ deg,
                                                  int* __restrict__ offs,
                                                  int* __restrict__ bsum) {
  __shared__ int s[256];
  int t = threadIdx.x, i = blockIdx.x * 256 + t;
  int v = deg[i];
  s[t] = v; __syncthreads();
  for (int d = 1; d < 256; d <<= 1) {
    int x = (t >= d) ? s[t - d] : 0; __syncthreads();
    s[t] += x; __syncthreads();
  }
  offs[i] = s[t] - v;
  if (t == 255) bsum[blockIdx.x] = s[t];
}
__global__ __launch_bounds__(256) void scan_bsum(int* __restrict__ bsum) {
  __shared__ int s[256];
  int t = threadIdx.x;
  int v = bsum[t];
  s[t] = v; __syncthreads();
  for (int d = 1; d < 256; d <<= 1) {
    int x = (t >= d) ? s[t - d] : 0; __syncthreads();
    s[t] += x; __syncthreads();
  }
  bsum[t] = s[t] - v;
}
__global__ __launch_bounds__(256) void add_offs(int* __restrict__ offs,
                                                const int* __restrict__ bsum,
                                                int* __restrict__ cursor) {
  int i = blockIdx.x * 256 + threadIdx.x;
  int o = offs[i] + bsum[blockIdx.x];
  offs[i] = o; cursor[i] = o;
}
// meta = uint-offset of XW[src, etype*128] in the u32 view: src*576 + et*64
__global__ __launch_bounds__(256) void fill_meta(const int* __restrict__ src,
                                                 const int* __restrict__ dst,
                                                 const int* __restrict__ et,
                                                 int* __restrict__ cursor,
                                                 uint* __restrict__ meta) {
  int e = blockIdx.x * 256 + threadIdx.x;
  if (e >= N_EDGES) return;
  int p = atomicAdd(&cursor[dst[e]], 1);
  meta[p] = (uint)src[e] * 576u + (uint)et[e] * 64u;
}

// ---------------- GEMM: XW[65536,1152] = hb[65536,128] @ Wcat ----------------
// 128x128 tile, K=128 single-stage, XOR-swizzled LDS staging (validated round 1).
__global__ __launch_bounds__(256) void gemm128(const ushort* __restrict__ A,
                                               const ushort* __restrict__ Bt,
                                               ushort* __restrict__ C, int ldc) {
  __shared__ char lds[65536];
  const int bm = blockIdx.x, bn = blockIdx.y;
  const char* Ag = (const char*)(A + (size_t)bm * 128 * 128);
  const char* Bg = (const char*)(Bt + (size_t)bn * 128 * 128);
  const int tid = threadIdx.x;
  const int wv = tid >> 6, ln = tid & 63;

#pragma unroll
  for (int it = 0; it < 8; ++it) {
    int chunk = it * 4096 + wv * 1024;          // wave-uniform LDS base
    int p = chunk + ln * 16;                    // linear lds byte pos
    int ps = p ^ (((p >> 8) & 7) << 4);         // inverse-swizzled global source
    gl_lds16(Ag + ps, lds + chunk);
    gl_lds16(Bg + ps, lds + 32768 + chunk);
  }
  asm volatile("s_waitcnt vmcnt(0)" ::: "memory");
  __syncthreads();

  const int wm = wv >> 1, wn = wv & 1;
  const int lr = ln & 15, kq = ln >> 4;
  f32x4 acc[4][4];
#pragma unroll
  for (int m = 0; m < 4; ++m)
#pragma unroll
    for (int n = 0; n < 4; ++n) acc[m][n] = (f32x4){0.f, 0.f, 0.f, 0.f};

#pragma unroll
  for (int kk = 0; kk < 4; ++kk) {
    const int kb = kk * 64 + kq * 16;
    short8 a[4], b[4];
#pragma unroll
    for (int m = 0; m < 4; ++m) {
      int row = wm * 64 + m * 16 + lr;
      int off = row * 256 + kb;
      a[m] = *(const short8*)(lds + (off ^ ((row & 7) << 4)));
    }
#pragma unroll
    for (int n = 0; n < 4; ++n) {
      int col = wn * 64 + n * 16 + lr;
      int off = col * 256 + kb;
      b[n] = *(const short8*)(lds + 32768 + (off ^ ((col & 7) << 4)));
    }
#pragma unroll
    for (int m = 0; m < 4; ++m)
#pragma unroll
      for (int n = 0; n < 4; ++n)
        acc[m][n] = __builtin_amdgcn_mfma_f32_16x16x32_bf16(a[m], b[n], acc[m][n], 0, 0, 0);
  }

#pragma unroll
  for (int m = 0; m < 4; ++m) {
    int row0 = bm * 128 + wm * 64 + m * 16 + kq * 4;
#pragma unroll
    for (int n = 0; n < 4; ++n) {
      int col = bn * 128 + wn * 64 + n * 16 + lr;
#pragma unroll
      for (int e = 0; e < 4; ++e)
        C[(size_t)(row0 + e) * ldc + col] = f2b(acc[m][n][e]);
    }
  }
}

// ---------------- gather: h_out[v] = relu( sum_e XW[src_e, r_e] + XW[v,self] + b ) ---
// Wave per node; 2 fp32 accumulators per lane; meta preload + readlane broadcast;
// 8/4-deep independent loads. No switch, no atomics.
__global__ __launch_bounds__(256) void gather_out(const uint* __restrict__ XWu,
                                                  const uint* __restrict__ meta,
                                                  const int* __restrict__ offs,
                                                  const int* __restrict__ deg,
                                                  const float* __restrict__ bias,
                                                  uint* __restrict__ hout) {
  int node = (blockIdx.x * 256 + threadIdx.x) >> 6;
  int ln = threadIdx.x & 63;
  int start = __builtin_amdgcn_readfirstlane(offs[node]);
  int ne = __builtin_amdgcn_readfirstlane(deg[node]);
  // issue self + bias loads early; they complete under the edge loop
  uint sv = XWu[(size_t)node * 576 + 512 + ln];
  float2 bv = ((const float2*)bias)[ln];
  float acc0 = 0.f, acc1 = 0.f;

  for (int c = 0; c < ne; c += 64) {
    int nc = ne - c;
    if (nc > 64) nc = 64;
    uint mv = meta[start + c + (ln < nc ? ln : nc - 1)];  // wave preload
    int i = 0;
    for (; i + 8 <= nc; i += 8) {
      uint v0 = XWu[(uint)__builtin_amdgcn_readlane((int)mv, i + 0) + ln];
      uint v1 = XWu[(uint)__builtin_amdgcn_readlane((int)mv, i + 1) + ln];
      uint v2 = XWu[(uint)__builtin_amdgcn_readlane((int)mv, i + 2) + ln];
      uint v3 = XWu[(uint)__builtin_amdgcn_readlane((int)mv, i + 3) + ln];
      uint v4 = XWu[(uint)__builtin_amdgcn_readlane((int)mv, i + 4) + ln];
      uint v5 = XWu[(uint)__builtin_amdgcn_readlane((int)mv, i + 5) + ln];
      uint v6 = XWu[(uint)__builtin_amdgcn_readlane((int)mv, i + 6) + ln];
      uint v7 = XWu[(uint)__builtin_amdgcn_readlane((int)mv, i + 7) + ln];
      acc0 += blo(v0); acc1 += bhi(v0);
      acc0 += blo(v1); acc1 += bhi(v1);
      acc0 += blo(v2); acc1 += bhi(v2);
      acc0 += blo(v3); acc1 += bhi(v3);
      acc0 += blo(v4); acc1 += bhi(v4);
      acc0 += blo(v5); acc1 += bhi(v5);
      acc0 += blo(v6); acc1 += bhi(v6);
      acc0 += blo(v7); acc1 += bhi(v7);
    }
    for (; i + 4 <= nc; i += 4) {
      uint v0 = XWu[(uint)__builtin_amdgcn_readlane((int)mv, i + 0) + ln];
      uint v1 = XWu[(uint)__builtin_amdgcn_readlane((int)mv, i + 1) + ln];
      uint v2 = XWu[(uint)__builtin_amdgcn_readlane((int)mv, i + 2) + ln];
      uint v3 = XWu[(uint)__builtin_amdgcn_readlane((int)mv, i + 3) + ln];
      acc0 += blo(v0); acc1 += bhi(v0);
      acc0 += blo(v1); acc1 += bhi(v1);
      acc0 += blo(v2); acc1 += bhi(v2);
      acc0 += blo(v3); acc1 += bhi(v3);
    }
    for (; i < nc; ++i) {
      uint v = XWu[(uint)__builtin_amdgcn_readlane((int)mv, i) + ln];
      acc0 += blo(v); acc1 += bhi(v);
    }
  }

  float r0 = fmaxf(acc0 + blo(sv) + bv.x, 0.f);
  float r1 = fmaxf(acc1 + bhi(sv) + bv.y, 0.f);
  hout[(size_t)node * 64 + ln] = (uint)f2b(r0) | ((uint)f2b(r1) << 16);
}

// ---------------- pool (2-stage) + classifier ----------------
__global__ __launch_bounds__(256) void pool_partial(const ushort* __restrict__ h2,
                                                    float* __restrict__ partial) {
  __shared__ float red[8][128];
  int blk = blockIdx.x, tid = threadIdx.x;
  int c = tid & 31, r = tid >> 5;
  float mx[4] = {0.f, 0.f, 0.f, 0.f};  // post-ReLU >= 0
  const ushort* base = h2 + (size_t)blk * 128 * DIM;
  for (int node = r; node < 128; node += 8) {
    ushort4 v = *(const ushort4*)(base + node * DIM + c * 4);
    mx[0] = fmaxf(mx[0], b2f(v.x));
    mx[1] = fmaxf(mx[1], b2f(v.y));
    mx[2] = fmaxf(mx[2], b2f(v.z));
    mx[3] = fmaxf(mx[3], b2f(v.w));
  }
#pragma unroll
  for (int j = 0; j < 4; ++j) red[r][c * 4 + j] = mx[j];
  __syncthreads();
  if (tid < 128) {
    float m = 0.f;
#pragma unroll
    for (int rr = 0; rr < 8; ++rr) m = fmaxf(m, red[rr][tid]);
    partial[(size_t)blk * 128 + tid] = m;
  }
}
__global__ __launch_bounds__(128) void classify(const float* __restrict__ partial,
                                                const float* __restrict__ Wc,
                                                const float* __restrict__ bc,
                                                float* __restrict__ out) {
  __shared__ float pooled[128];
  int g = blockIdx.x, tid = threadIdx.x;
  const float* p = partial + (size_t)g * 8 * 128;
  float m = 0.f;
#pragma unroll
  for (int b = 0; b < 8; ++b) m = fmaxf(m, p[b * 128 + tid]);
  pooled[tid] = m;
  __syncthreads();
  if (tid < 10) {
    float s = bc[tid];
    for (int d = 0; d < DIM; ++d) s += pooled[d] * Wc[d * 10 + tid];
    out[g * 10 + tid] = s;
  }
}

extern "C" void kernel_launch(void* const* d_in, const int* in_sizes, int n_in,
                              void* d_out, int out_size, void* d_ws, size_t ws_size,
                              hipStream_t stream) {
  const float* h       = (const float*)d_in[0];
  const float* W1      = (const float*)d_in[1];
  const float* W1_self = (const float*)d_in[2];
  const float* b1      = (const float*)d_in[3];
  const float* W2      = (const float*)d_in[4];
  const float* W2_self = (const float*)d_in[5];
  const float* b2      = (const float*)d_in[6];
  const float* Wc      = (const float*)d_in[7];
  const float* bc      = (const float*)d_in[8];
  const int* src   = (const int*)d_in[9];
  const int* dst   = (const int*)d_in[10];
  const int* etype = (const int*)d_in[11];
  float* out = (float*)d_out;

  char* ws = (char*)d_ws;
  ushort* XW     = (ushort*)(ws);
  ushort* hb     = (ushort*)(ws + 150994944);
  ushort* h1b    = (ushort*)(ws + 167772160);
  ushort* hb2    = (ushort*)(ws + 184549376);
  ushort* Wt1c   = (ushort*)(ws + 201326592);
  ushort* Wt2c   = (ushort*)(ws + 201621504);
  int*    deg    = (int*)(ws + 201916416);
  int*    offs   = (int*)(ws + 202178560);
  int*    cursor = (int*)(ws + 202440704);
  int*    bsum   = (int*)(ws + 202702848);
  uint*   meta   = (uint*)(ws + 202703872);
  float*  partial= (float*)(ws + 205849600);

  const int n4_h = N_NODES * DIM / 4;        // 2,097,152
  const int g_h = n4_h / 256;                // 8192
  const int g_edge = (N_EDGES + 255) / 256;  // 3072
  const int g_gather = N_NODES / 4;          // 16384 (4 waves/block)
  dim3 gemm_grid(N_NODES / 128, NT);

  // --- prep ---
  f32_to_bf16_vec<<<g_h, 256, 0, stream>>>(h, hb, n4_h);
  wconv_all<<<18, 256, 0, stream>>>(W1, W1_self, W2, W2_self, Wt1c, Wt2c);

  // --- CSR by dst (shared by both layers) ---
  hipMemsetAsync(deg, 0, N_NODES * sizeof(int), stream);
  hist_dst<<<g_edge, 256, 0, stream>>>(dst, deg);
  scan_block<<<256, 256, 0, stream>>>(deg, offs, bsum);
  scan_bsum<<<1, 256, 0, stream>>>(bsum);
  add_offs<<<256, 256, 0, stream>>>(offs, bsum, cursor);
  fill_meta<<<g_edge, 256, 0, stream>>>(src, dst, etype, cursor, meta);

  // --- layer 1: XW = hb @ Wcat1 ; h1 = relu(gather + self + b1) ---
  gemm128<<<gemm_grid, 256, 0, stream>>>(hb, Wt1c, XW, XW_LD);
  gather_out<<<g_gather, 256, 0, stream>>>((const uint*)XW, meta, offs, deg, b1, (uint*)h1b);

  // --- layer 2 ---
  gemm128<<<gemm_grid, 256, 0, stream>>>(h1b, Wt2c, XW, XW_LD);
  gather_out<<<g_gather, 256, 0, stream>>>((const uint*)XW, meta, offs, deg, b2, (uint*)hb2);

  // --- pool + classify ---
  pool_partial<<<512, 256, 0, stream>>>(hb2, partial);
  classify<<<N_GRAPHS, 128, 0, stream>>>(partial, Wc, bc, out);

  (void)in_sizes; (void)n_in; (void)out_size; (void)ws_size;
}